// Round 4
// baseline (132.450 us; speedup 1.0000x reference)
//
#include <hip/hip_runtime.h>

// CapsuleConv2d fused, MI355X gfx950. ALL I/O FP32.
// B=2, C_in=128 (G=8 x M=16), 32x32, 3x3 pad 1, O=16, L=16 -> C_out=256.
// k-means (dot) routing 3 iters + squash.
//
// Main kernel: 1 block/pixel, thread t=o*16+l, u[72] in VGPRs (nested 8x9
// unrolled loops -> all indices constant -> SROA must promote).
// Patch via wave-uniform s_load from im2col buffer P; NO LDS in main kernel.
// 16-lane reductions via DPP row_ror (VALU pipe).
// Prep kernel: coalesced im2col via LDS row staging + weight transpose.

#define NPRI 72
#define WT_ELEMS (9 * 256 * 16)          // 147456 B
#define P_ELEMS  (2048 * 1152)           // 9437184 B

__device__ __forceinline__ float dpp_add16(float x) {
    // sum across each aligned 16-lane group, broadcast to all 16 lanes.
    float s = x;
    s += __int_as_float(__builtin_amdgcn_update_dpp(
            0, __float_as_int(s), 0x128, 0xF, 0xF, true));  // row_ror:8
    s += __int_as_float(__builtin_amdgcn_update_dpp(
            0, __float_as_int(s), 0x124, 0xF, 0xF, true));  // row_ror:4
    s += __int_as_float(__builtin_amdgcn_update_dpp(
            0, __float_as_int(s), 0x122, 0xF, 0xF, true));  // row_ror:2
    s += __int_as_float(__builtin_amdgcn_update_dpp(
            0, __float_as_int(s), 0x121, 0xF, 0xF, true));  // row_ror:1
    return s;
}

__device__ __forceinline__ float frcp(float x) {
    return __builtin_amdgcn_rcpf(x);
}

// Routing + squash on u[72]; all u[] indices compile-time constants.
#define ROUTING_SQUASH(u, res)                                               \
  do {                                                                       \
    float v_ = 0.0f;                                                         \
    _Pragma("unroll")                                                        \
    for (int g_ = 0; g_ < 8; ++g_) {                                         \
      _Pragma("unroll")                                                      \
      for (int ij_ = 0; ij_ < 9; ++ij_) v_ += u[g_ * 9 + ij_];               \
    }                                                                        \
    v_ *= (1.0f / NPRI);                                                     \
    _Pragma("unroll 1")                                                      \
    for (int it_ = 0; it_ < 3; ++it_) {                                      \
      float s_ = dpp_add16(v_ * v_);                                         \
      float vn_ = v_ * frcp(fmaxf(sqrtf(s_), 1e-12f));                       \
      float ssum_ = 0.0f, vacc_ = 0.0f;                                      \
      _Pragma("unroll")                                                      \
      for (int g_ = 0; g_ < 8; ++g_) {                                       \
        _Pragma("unroll")                                                    \
        for (int ij_ = 0; ij_ < 9; ++ij_) {                                  \
          float uu_ = u[g_ * 9 + ij_];                                       \
          float p_ = dpp_add16(uu_ * vn_);                                   \
          float e_ = __expf(p_);                                             \
          ssum_ += e_;                                                       \
          vacc_ = fmaf(e_, uu_, vacc_);                                      \
        }                                                                    \
      }                                                                      \
      v_ = vacc_ * frcp(ssum_);                                              \
    }                                                                        \
    float sq_ = dpp_add16(v_ * v_);                                          \
    res = v_ * sqrtf(sq_) * frcp(1.0f + sq_);                                \
  } while (0)

// ---- prep: blocks [0,64) im2col for one (b,h) row; [64,208) Wt transpose ----
__global__ __launch_bounds__(256)
void prep_kernel(const float* __restrict__ x, const float* __restrict__ W,
                 float* __restrict__ Wt, float* __restrict__ P) {
    const int blk = blockIdx.x;
    const int tid = threadIdx.x;
    if (blk >= 64) {
        // Wt[(ij*256+t)*16+m] = W[(t*16+m)*9+ij]
        int idx = (blk - 64) * 256 + tid;        // 0..36863
        int ij = idx >> 12;
        int r  = idx & 4095;
        int tt = r >> 4;
        int m  = r & 15;
        Wt[idx] = W[(tt * 16 + m) * 9 + ij];
        return;
    }
    // im2col for pixels (b, h, 0..31)
    __shared__ float xs[128 * 99];               // [c][hi(3)][w pad 33]
    const int b = blk >> 5;
    const int h = blk & 31;
    const float* xb = x + b * (128 * 32 * 32);

    // coalesced load: 128*3*32 = 12288 floats; lane-adjacent -> adjacent w
    #pragma unroll 4
    for (int it = 0; it < 48; ++it) {
        int flat = it * 256 + tid;
        int c  = flat / 96;
        int r  = flat - c * 96;
        int hi = r >> 5;                          // 0..2
        int w  = r & 31;
        int hh = h + hi - 1;
        float v = 0.0f;
        if ((unsigned)hh < 32u) v = xb[(c * 32 + hh) * 32 + w];
        xs[c * 99 + hi * 33 + w] = v;
    }
    __syncthreads();

    // coalesced store: P[(pix)*1152 + ij*128 + c], lane-adjacent -> adjacent c
    float* Pp = P + (size_t)(b * 1024 + h * 32) * 1152;
    #pragma unroll 4
    for (int it = 0; it < 144; ++it) {
        int flat = it * 256 + tid;                // 0..36863 = w*1152 + ij*128 + c
        int w  = flat / 1152;
        int r  = flat - w * 1152;
        int ij = r >> 7;
        int c  = r & 127;
        int di = ij / 3, dj = ij - di * 3;
        int ww = w + dj - 1;
        float v = 0.0f;
        if ((unsigned)ww < 32u) v = xs[c * 99 + di * 33 + ww];
        Pp[flat] = v;
    }
}

// ---- main kernel: no LDS, patch via scalar loads, u[72] in VGPRs ----
__global__ __launch_bounds__(256, 1)
void capsule_s_kernel(const float* __restrict__ P,
                      const float* __restrict__ Wt,
                      float* __restrict__ out) {
    const int pix = blockIdx.x;              // 2048
    const int b = pix >> 10;
    const int h = (pix >> 5) & 31;
    const int w = pix & 31;
    const int t = threadIdx.x;               // t = o*16 + l

    const float* __restrict__ Pp = P + pix * 1152;   // wave-uniform base

    float u[NPRI];
    #pragma unroll
    for (int ij = 0; ij < 9; ++ij) {
        float wr[16];
        const float* wp = Wt + (ij * 256 + t) * 16;
        #pragma unroll
        for (int m = 0; m < 16; ++m) wr[m] = wp[m];

        #pragma unroll
        for (int g = 0; g < 8; ++g) {
            const float* sp = Pp + ij * 128 + g * 16;  // uniform -> s_load
            float acc = 0.0f;
            #pragma unroll
            for (int m = 0; m < 16; ++m)
                acc = fmaf(sp[m], wr[m], acc);         // v_fmac: sgpr x vgpr
            u[g * 9 + ij] = acc;
        }
    }

    float res;
    ROUTING_SQUASH(u, res);
    out[((b * 256 + t) * 32 + h) * 32 + w] = res;
}

// ---- fallback (small ws): LDS staging variant ----
template <bool USE_WT>
__global__ __launch_bounds__(256, 1)
void capsule_lds_kernel(const float* __restrict__ x,
                        const float* __restrict__ Wt,
                        const float* __restrict__ Wraw,
                        float* __restrict__ out) {
    __shared__ float patch[9 * 128];
    const int blk = blockIdx.x;
    const int b = blk >> 10;
    const int h = (blk >> 5) & 31;
    const int w = blk & 31;
    const int t = threadIdx.x;

    const float* xb = x + b * (128 * 32 * 32);
    for (int idx = t; idx < 1152; idx += 256) {
        int c  = idx / 9;
        int ij = idx - c * 9;
        int di = ij / 3, dj = ij - di * 3;
        int hh = h + di - 1, ww = w + dj - 1;
        float v = 0.0f;
        if ((unsigned)hh < 32u && (unsigned)ww < 32u)
            v = xb[(c * 32 + hh) * 32 + ww];
        patch[ij * 128 + c] = v;
    }
    __syncthreads();

    float u[NPRI];
    #pragma unroll
    for (int ij = 0; ij < 9; ++ij) {
        float wr[16];
        if (USE_WT) {
            const float* wp = Wt + (ij * 256 + t) * 16;
            #pragma unroll
            for (int m = 0; m < 16; ++m) wr[m] = wp[m];
        } else {
            #pragma unroll
            for (int m = 0; m < 16; ++m)
                wr[m] = Wraw[(t * 16 + m) * 9 + ij];
        }
        #pragma unroll
        for (int g = 0; g < 8; ++g) {
            float acc = 0.0f;
            #pragma unroll
            for (int m = 0; m < 16; ++m)
                acc = fmaf(patch[ij * 128 + g * 16 + m], wr[m], acc);
            u[g * 9 + ij] = acc;
        }
    }

    float res;
    ROUTING_SQUASH(u, res);
    out[((b * 256 + t) * 32 + h) * 32 + w] = res;
}

extern "C" void kernel_launch(void* const* d_in, const int* in_sizes, int n_in,
                              void* d_out, int out_size, void* d_ws, size_t ws_size,
                              hipStream_t stream) {
    const float* x = (const float*)d_in[0];   // [2,128,32,32]
    const float* W = (const float*)d_in[1];   // [16,16,16,3,3]
    float* out = (float*)d_out;               // [2,256,32,32]
    float* Wt = (float*)d_ws;
    float* P  = Wt + WT_ELEMS;

    const size_t need_full = (size_t)(WT_ELEMS + P_ELEMS) * sizeof(float);
    const size_t need_wt   = (size_t)WT_ELEMS * sizeof(float);

    if (ws_size >= need_full) {
        prep_kernel<<<208, 256, 0, stream>>>(x, W, Wt, P);
        capsule_s_kernel<<<2048, 256, 0, stream>>>(P, Wt, out);
    } else if (ws_size >= need_wt) {
        prep_kernel<<<144 + 64, 256, 0, stream>>>(x, W, Wt, (float*)nullptr);
        capsule_lds_kernel<true><<<2048, 256, 0, stream>>>(x, Wt, W, out);
    } else {
        capsule_lds_kernel<false><<<2048, 256, 0, stream>>>(x, Wt, W, out);
    }
}

// Round 5
// 118.202 us; speedup vs baseline: 1.1205x; 1.1205x over previous
//
#include <hip/hip_runtime.h>

// CapsuleConv2d fused, MI355X gfx950. ALL I/O FP32.
// B=2, C_in=128 (G=8 x M=16), 32x32, 3x3 pad 1, O=16, L=16 -> C_out=256.
// k-means (dot) routing 3 iters + squash.
//
// Main kernel: 1 block/pixel, thread t=o*16+l, u[72] per-thread.
// Patch via wave-uniform s_load from im2col buffer P (no LDS, no ds_read).
// 16-lane reductions via DPP row_ror on the VALU pipe, batched x4 so
// independent chains fill DPP hazard slots.
// Prep: 256 blocks (8 pixels each) LDS-transpose im2col + 144 blocks Wt.

#define NPRI 72
#define WT_ELEMS (9 * 256 * 16)          // 147456 floats
#define P_ELEMS  (2048 * 1152)           // 2359296 floats

#define DPP_ADD(a, ctrl)                                                     \
  a += __int_as_float(__builtin_amdgcn_update_dpp(                           \
          0, __float_as_int(a), ctrl, 0xF, 0xF, true))

// 4 independent 16-lane all-reduce-sum chains, interleaved.
#define RED16_X4(a0, a1, a2, a3)                                             \
  do {                                                                       \
    DPP_ADD(a0, 0x128); DPP_ADD(a1, 0x128); DPP_ADD(a2, 0x128); DPP_ADD(a3, 0x128); \
    DPP_ADD(a0, 0x124); DPP_ADD(a1, 0x124); DPP_ADD(a2, 0x124); DPP_ADD(a3, 0x124); \
    DPP_ADD(a0, 0x122); DPP_ADD(a1, 0x122); DPP_ADD(a2, 0x122); DPP_ADD(a3, 0x122); \
    DPP_ADD(a0, 0x121); DPP_ADD(a1, 0x121); DPP_ADD(a2, 0x121); DPP_ADD(a3, 0x121); \
  } while (0)

__device__ __forceinline__ float dpp_add16(float x) {
    float s = x;
    DPP_ADD(s, 0x128); DPP_ADD(s, 0x124); DPP_ADD(s, 0x122); DPP_ADD(s, 0x121);
    return s;
}

__device__ __forceinline__ float frcp(float x) {
    return __builtin_amdgcn_rcpf(x);
}

// Routing + squash on u[72]; all u[] indices compile-time constants.
// n-loop batched x4: independent DPP chains interleave (hazard-slot fill).
#define ROUTING_SQUASH(u, res)                                               \
  do {                                                                       \
    float v_ = 0.0f;                                                         \
    _Pragma("unroll")                                                        \
    for (int n_ = 0; n_ < NPRI; ++n_) v_ += u[n_];                           \
    v_ *= (1.0f / NPRI);                                                     \
    _Pragma("unroll 1")                                                      \
    for (int it_ = 0; it_ < 3; ++it_) {                                      \
      float s_ = dpp_add16(v_ * v_);                                         \
      float vn_ = v_ * frcp(fmaxf(sqrtf(s_), 1e-12f));                       \
      float ssum_ = 0.0f, vacc_ = 0.0f;                                      \
      _Pragma("unroll")                                                      \
      for (int nb_ = 0; nb_ < NPRI; nb_ += 4) {                              \
        float a0_ = u[nb_ + 0] * vn_;                                        \
        float a1_ = u[nb_ + 1] * vn_;                                        \
        float a2_ = u[nb_ + 2] * vn_;                                        \
        float a3_ = u[nb_ + 3] * vn_;                                        \
        RED16_X4(a0_, a1_, a2_, a3_);                                        \
        float e0_ = __expf(a0_);                                             \
        float e1_ = __expf(a1_);                                             \
        float e2_ = __expf(a2_);                                             \
        float e3_ = __expf(a3_);                                             \
        ssum_ += (e0_ + e1_) + (e2_ + e3_);                                  \
        vacc_ = fmaf(e0_, u[nb_ + 0], vacc_);                                \
        vacc_ = fmaf(e1_, u[nb_ + 1], vacc_);                                \
        vacc_ = fmaf(e2_, u[nb_ + 2], vacc_);                                \
        vacc_ = fmaf(e3_, u[nb_ + 3], vacc_);                                \
      }                                                                      \
      v_ = vacc_ * frcp(ssum_);                                              \
    }                                                                        \
    float sq_ = dpp_add16(v_ * v_);                                          \
    res = v_ * sqrtf(sq_) * frcp(1.0f + sq_);                                \
  } while (0)

// ---- prep ----
// blocks [0,256): im2col for 8 pixels (b, h, w0..w0+7) via LDS transpose
// blocks [256,400): Wt[(ij*256+t)*16+m] = W[(t*16+m)*9+ij]
__global__ __launch_bounds__(256)
void prep_kernel(const float* __restrict__ x, const float* __restrict__ W,
                 float* __restrict__ Wt, float* __restrict__ P) {
    const int blk = blockIdx.x;
    const int tid = threadIdx.x;
    if (blk >= 256) {
        int idx = (blk - 256) * 256 + tid;       // 0..36863
        int ij = idx >> 12;
        int r  = idx & 4095;
        int tt = r >> 4;
        int m  = r & 15;
        Wt[idx] = W[(tt * 16 + m) * 9 + ij];
        return;
    }
    // xs[c][hi][wl]: stride 33 over c -> conflict-free lane-adjacent-c reads
    __shared__ float xs[128 * 33];               // 16.9 KB
    const int b  = blk >> 7;
    const int h  = (blk >> 2) & 31;
    const int w0 = (blk & 3) * 8;
    const float* xb = x + b * (128 * 32 * 32);

    // load 128c x 3hh x 10ww = 3840 floats, w-contiguous segments
    #pragma unroll
    for (int k = 0; k < 15; ++k) {
        int flat = k * 256 + tid;
        if (flat < 3840) {
            int c  = flat / 30;
            int r  = flat - c * 30;
            int hi = r / 10;
            int wl = r - hi * 10;
            int hh = h + hi - 1;
            int ww = w0 + wl - 1;
            float v = 0.0f;
            if ((unsigned)hh < 32u && (unsigned)ww < 32u)
                v = xb[(c * 32 + hh) * 32 + ww];
            xs[c * 33 + hi * 10 + wl] = v;
        }
    }
    __syncthreads();

    // store 8 pixels x 1152, fully coalesced (lane-adjacent -> adjacent c)
    float* Pp = P + (size_t)(b * 1024 + h * 32 + w0) * 1152;
    #pragma unroll
    for (int k = 0; k < 36; ++k) {
        int flat = k * 256 + tid;                // p*1152 + ij*128 + c
        int p  = flat / 1152;
        int r  = flat - p * 1152;
        int ij = r >> 7;
        int c  = r & 127;
        int di = ij / 3, dj = ij - di * 3;
        Pp[flat] = xs[c * 33 + di * 10 + (p + dj)];
    }
}

// ---- main kernel: no LDS, patch via scalar loads ----
__global__ __launch_bounds__(256, 1)
void capsule_s_kernel(const float* __restrict__ P,
                      const float* __restrict__ Wt,
                      float* __restrict__ out) {
    const int pix = blockIdx.x;              // 2048
    const int b = pix >> 10;
    const int h = (pix >> 5) & 31;
    const int w = pix & 31;
    const int t = threadIdx.x;               // t = o*16 + l

    const float* __restrict__ Pp = P + pix * 1152;   // wave-uniform base

    float u[NPRI];
    #pragma unroll
    for (int ij = 0; ij < 9; ++ij) {
        float wr[16];
        const float* wp = Wt + (ij * 256 + t) * 16;
        #pragma unroll
        for (int m = 0; m < 16; ++m) wr[m] = wp[m];

        #pragma unroll
        for (int g = 0; g < 8; ++g) {
            const float* sp = Pp + ij * 128 + g * 16;  // uniform -> s_load
            float acc = 0.0f;
            #pragma unroll
            for (int m = 0; m < 16; ++m)
                acc = fmaf(sp[m], wr[m], acc);         // v_fmac: sgpr x vgpr
            u[g * 9 + ij] = acc;
        }
    }

    float res;
    ROUTING_SQUASH(u, res);
    out[((b * 256 + t) * 32 + h) * 32 + w] = res;
}

// ---- fallback (small ws): LDS staging variant ----
template <bool USE_WT>
__global__ __launch_bounds__(256, 1)
void capsule_lds_kernel(const float* __restrict__ x,
                        const float* __restrict__ Wt,
                        const float* __restrict__ Wraw,
                        float* __restrict__ out) {
    __shared__ float patch[9 * 128];
    const int blk = blockIdx.x;
    const int b = blk >> 10;
    const int h = (blk >> 5) & 31;
    const int w = blk & 31;
    const int t = threadIdx.x;

    const float* xb = x + b * (128 * 32 * 32);
    for (int idx = t; idx < 1152; idx += 256) {
        int c  = idx / 9;
        int ij = idx - c * 9;
        int di = ij / 3, dj = ij - di * 3;
        int hh = h + di - 1, ww = w + dj - 1;
        float v = 0.0f;
        if ((unsigned)hh < 32u && (unsigned)ww < 32u)
            v = xb[(c * 32 + hh) * 32 + ww];
        patch[ij * 128 + c] = v;
    }
    __syncthreads();

    float u[NPRI];
    #pragma unroll
    for (int ij = 0; ij < 9; ++ij) {
        float wr[16];
        if (USE_WT) {
            const float* wp = Wt + (ij * 256 + t) * 16;
            #pragma unroll
            for (int m = 0; m < 16; ++m) wr[m] = wp[m];
        } else {
            #pragma unroll
            for (int m = 0; m < 16; ++m)
                wr[m] = Wraw[(t * 16 + m) * 9 + ij];
        }
        #pragma unroll
        for (int g = 0; g < 8; ++g) {
            float acc = 0.0f;
            #pragma unroll
            for (int m = 0; m < 16; ++m)
                acc = fmaf(patch[ij * 128 + g * 16 + m], wr[m], acc);
            u[g * 9 + ij] = acc;
        }
    }

    float res;
    ROUTING_SQUASH(u, res);
    out[((b * 256 + t) * 32 + h) * 32 + w] = res;
}

extern "C" void kernel_launch(void* const* d_in, const int* in_sizes, int n_in,
                              void* d_out, int out_size, void* d_ws, size_t ws_size,
                              hipStream_t stream) {
    const float* x = (const float*)d_in[0];   // [2,128,32,32]
    const float* W = (const float*)d_in[1];   // [16,16,16,3,3]
    float* out = (float*)d_out;               // [2,256,32,32]
    float* Wt = (float*)d_ws;
    float* P  = Wt + WT_ELEMS;

    const size_t need_full = (size_t)(WT_ELEMS + P_ELEMS) * sizeof(float);
    const size_t need_wt   = (size_t)WT_ELEMS * sizeof(float);

    if (ws_size >= need_full) {
        prep_kernel<<<400, 256, 0, stream>>>(x, W, Wt, P);
        capsule_s_kernel<<<2048, 256, 0, stream>>>(P, Wt, out);
    } else if (ws_size >= need_wt) {
        prep_kernel<<<256 + 144, 256, 0, stream>>>(x, W, Wt, (float*)nullptr);
        capsule_lds_kernel<true><<<2048, 256, 0, stream>>>(x, Wt, W, out);
    } else {
        capsule_lds_kernel<false><<<2048, 256, 0, stream>>>(x, Wt, W, out);
    }
}

// Round 6
// 101.706 us; speedup vs baseline: 1.3023x; 1.1622x over previous
//
#include <hip/hip_runtime.h>

// CapsuleConv2d fused, MI355X gfx950. ALL I/O FP32.
// B=2, C_in=128 (G=8 x M=16), 32x32, 3x3 pad 1, O=16, L=16 -> C_out=256.
// k-means (dot) routing 3 iters + squash.
//
// v3: 1 block/pixel. Phase 1 (thread = (o,l)): priors u[72] via SGPR patch
// (s_load from xT) x VGPR weights. Then ONE LDS transpose of u (u is
// invariant across routing iters). Phase 2 (thread = (o,nc)): thread owns
// 4-5 full u-rows (all 16 l) in registers -> routing is register-local:
// logits = local dots, exp only on owned rows (14 vs 216 exps), v-update
// via 16-reg DPP all-reduce. No LDS and no per-n cross-lane reduce in iters.

#define NPRI 72
#define XT_ELEMS (2 * 32 * 32 * 128)   // 1 MB
#define WT_ELEMS (9 * 256 * 16)        // 576 KB

#define DPP_ADD(a, ctrl)                                                     \
  a += __int_as_float(__builtin_amdgcn_update_dpp(                           \
          0, __float_as_int(a), ctrl, 0xF, 0xF, true))

__device__ __forceinline__ float dpp_add16(float x) {
    // sum across each aligned 16-lane group, broadcast to all 16 lanes.
    float s = x;
    DPP_ADD(s, 0x128); DPP_ADD(s, 0x124); DPP_ADD(s, 0x122); DPP_ADD(s, 0x121);
    return s;
}

__device__ __forceinline__ float frcp(float x) {
    return __builtin_amdgcn_rcpf(x);
}

// ---- prep: blocks [0,64) x-transpose, [64,208) weight transpose ----
// xT[b][h][w][c] = x[b][c][h][w];  Wt[(ij*256+t)*16+m] = W[(t*16+m)*9+ij]
__global__ __launch_bounds__(256)
void prep_kernel(const float* __restrict__ x, const float* __restrict__ W,
                 float* __restrict__ xT, float* __restrict__ Wt) {
    const int blk = blockIdx.x;
    const int tid = threadIdx.x;
    if (blk < 64) {
        __shared__ float xs[128 * 33];
        const int b = blk >> 5, h = blk & 31;
        const float* xb = x + b * (128 * 32 * 32) + h * 32;  // [c*1024 + w]
        #pragma unroll
        for (int k = 0; k < 16; ++k) {
            int idx = k * 256 + tid;
            int c = idx >> 5, w = idx & 31;
            xs[c * 33 + w] = xb[c * 1024 + w];   // coalesced read
        }
        __syncthreads();
        float* xo = xT + (b * 32 + h) * 32 * 128;
        #pragma unroll
        for (int k = 0; k < 16; ++k) {
            int idx = k * 256 + tid;
            int w = idx >> 7, c = idx & 127;
            xo[w * 128 + c] = xs[c * 33 + w];    // coalesced write, cf-free read
        }
    } else {
        int idx = (blk - 64) * 256 + tid;        // 0..36863
        int ij = idx >> 12;
        int r  = idx & 4095;
        int tt = r >> 4;
        int m  = r & 15;
        Wt[idx] = W[(tt * 16 + m) * 9 + ij];
    }
}

// ---- main kernel v3 ----
__global__ __launch_bounds__(256, 3)
void capsule_v3(const float* __restrict__ xT, const float* __restrict__ Wt,
                float* __restrict__ out) {
    __shared__ float uTs[36 * 260];          // 37.4 KB, two-chunk transpose
    const int pix = blockIdx.x;              // 2048
    const int b = pix >> 10, h = (pix >> 5) & 31, w = pix & 31;
    const int t = threadIdx.x;
    const int o = t >> 4, nc = t & 15;       // phase1: l == nc

    // ---- phase 1: priors, thread=(o,l) ----
    float u[NPRI];
    #pragma unroll
    for (int n = 0; n < NPRI; ++n) u[n] = 0.0f;

    #pragma unroll
    for (int ij = 0; ij < 9; ++ij) {
        const int di = ij / 3, dj = ij % 3;
        const int hh = h + di - 1, ww = w + dj - 1;
        if ((unsigned)hh < 32u && (unsigned)ww < 32u) {   // block-uniform
            const float* sp = xT + ((b * 32 + hh) * 32 + ww) * 128; // s_load
            const float* wp = Wt + (ij * 256 + t) * 16;
            float wr[16];
            #pragma unroll
            for (int m = 0; m < 16; ++m) wr[m] = wp[m];
            #pragma unroll
            for (int g = 0; g < 8; ++g) {
                float acc = 0.0f;
                #pragma unroll
                for (int m = 0; m < 16; ++m)
                    acc = fmaf(sp[g * 16 + m], wr[m], acc);
                u[g * 9 + ij] = acc;
            }
        }
    }

    // ---- transpose u -> ut[k][j] (thread=(o,nc) owns rows n=nc+16k) ----
    float ut[5][16];
    #pragma unroll
    for (int n = 0; n < 36; ++n) uTs[n * 260 + t] = u[n];
    __syncthreads();
    #pragma unroll
    for (int k = 0; k < 3; ++k) {            // n = nc+16k < 36 possible for k<3
        int n = nc + 16 * k;
        if (n < 36) {
            #pragma unroll
            for (int j = 0; j < 16; ++j) ut[k][j] = uTs[n * 260 + o * 16 + j];
        }
    }
    __syncthreads();
    #pragma unroll
    for (int n = 36; n < NPRI; ++n) uTs[(n - 36) * 260 + t] = u[n];
    __syncthreads();
    #pragma unroll
    for (int k = 2; k < 5; ++k) {            // n = nc+16k >= 36 possible for k>=2
        int n = nc + 16 * k;
        if (n >= 36 && n < NPRI) {
            #pragma unroll
            for (int j = 0; j < 16; ++j)
                ut[k][j] = uTs[(n - 36) * 260 + o * 16 + j];
        }
    }
    const bool has5 = (nc < 8);              // row n=64+nc exists only for nc<8

    // ---- init v = mean over n (broadcast to all lanes of group) ----
    float va[16];
    #pragma unroll
    for (int j = 0; j < 16; ++j) {
        float s = ((ut[0][j] + ut[1][j]) + (ut[2][j] + ut[3][j]));
        if (has5) s += ut[4][j];
        va[j] = s;
    }
    #pragma unroll
    for (int j = 0; j < 16; ++j) va[j] = dpp_add16(va[j]) * (1.0f / NPRI);

    // ---- 3 routing iterations, registers only ----
    #pragma unroll 1
    for (int it = 0; it < 3; ++it) {
        float ss = 0.0f;
        #pragma unroll
        for (int j = 0; j < 16; ++j) ss = fmaf(va[j], va[j], ss);
        float inv = frcp(fmaxf(sqrtf(ss), 1e-12f));

        float e[5];
        float ssum = 0.0f;
        #pragma unroll
        for (int k = 0; k < 5; ++k) {
            if (k < 4) {
                float d = 0.0f;
                #pragma unroll
                for (int j = 0; j < 16; ++j) d = fmaf(ut[k][j], va[j], d);
                e[k] = __expf(d * inv);
                ssum += e[k];
            } else if (has5) {
                float d = 0.0f;
                #pragma unroll
                for (int j = 0; j < 16; ++j) d = fmaf(ut[4][j], va[j], d);
                e[4] = __expf(d * inv);
                ssum += e[4];
            }
        }
        ssum = dpp_add16(ssum);
        float rs = frcp(ssum);

        #pragma unroll
        for (int j = 0; j < 16; ++j) {
            float pv = fmaf(e[0], ut[0][j],
                       fmaf(e[1], ut[1][j],
                       fmaf(e[2], ut[2][j], e[3] * ut[3][j])));
            if (has5) pv = fmaf(e[4], ut[4][j], pv);
            va[j] = dpp_add16(pv) * rs;
        }
    }

    // ---- squash (all lanes hold full va[16] of their group) ----
    float ss = 0.0f;
    #pragma unroll
    for (int j = 0; j < 16; ++j) ss = fmaf(va[j], va[j], ss);
    float scale = sqrtf(ss) * frcp(1.0f + ss);

    // select va[nc] via cndmask ladder (res for channel t = o*16+nc)
    float c8[8], c4[4], c2[2];
    #pragma unroll
    for (int j = 0; j < 8; ++j) c8[j] = (nc & 8) ? va[j + 8] : va[j];
    #pragma unroll
    for (int j = 0; j < 4; ++j) c4[j] = (nc & 4) ? c8[j + 4] : c8[j];
    #pragma unroll
    for (int j = 0; j < 2; ++j) c2[j] = (nc & 2) ? c4[j + 2] : c4[j];
    float res = ((nc & 1) ? c2[1] : c2[0]) * scale;

    out[((b * 256 + t) * 32 + h) * 32 + w] = res;
}

// ---- fallback (tiny ws): self-contained, old DPP routing ----
__global__ __launch_bounds__(256, 1)
void capsule_fb(const float* __restrict__ x, const float* __restrict__ Wraw,
                float* __restrict__ out) {
    __shared__ float patch[9 * 128];
    const int blk = blockIdx.x;
    const int b = blk >> 10, h = (blk >> 5) & 31, w = blk & 31;
    const int t = threadIdx.x;

    const float* xb = x + b * (128 * 32 * 32);
    for (int idx = t; idx < 1152; idx += 256) {
        int c = idx / 9, ij = idx - c * 9;
        int di = ij / 3, dj = ij - di * 3;
        int hh = h + di - 1, ww = w + dj - 1;
        float v = 0.0f;
        if ((unsigned)hh < 32u && (unsigned)ww < 32u)
            v = xb[(c * 32 + hh) * 32 + ww];
        patch[ij * 128 + c] = v;
    }
    __syncthreads();

    float u[NPRI];
    #pragma unroll
    for (int ij = 0; ij < 9; ++ij) {
        float wr[16];
        #pragma unroll
        for (int m = 0; m < 16; ++m) wr[m] = Wraw[(t * 16 + m) * 9 + ij];
        #pragma unroll
        for (int g = 0; g < 8; ++g) {
            float acc = 0.0f;
            #pragma unroll
            for (int m = 0; m < 16; ++m)
                acc = fmaf(patch[ij * 128 + g * 16 + m], wr[m], acc);
            u[g * 9 + ij] = acc;
        }
    }

    float v = 0.0f;
    #pragma unroll
    for (int n = 0; n < NPRI; ++n) v += u[n];
    v *= (1.0f / NPRI);
    #pragma unroll 1
    for (int it = 0; it < 3; ++it) {
        float s = dpp_add16(v * v);
        float vn = v * frcp(fmaxf(sqrtf(s), 1e-12f));
        float ssum = 0.0f, vacc = 0.0f;
        #pragma unroll
        for (int n = 0; n < NPRI; ++n) {
            float p = dpp_add16(u[n] * vn);
            float e = __expf(p);
            ssum += e;
            vacc = fmaf(e, u[n], vacc);
        }
        v = vacc * frcp(ssum);
    }
    float s = dpp_add16(v * v);
    float res = v * sqrtf(s) * frcp(1.0f + s);
    out[((b * 256 + t) * 32 + h) * 32 + w] = res;
}

extern "C" void kernel_launch(void* const* d_in, const int* in_sizes, int n_in,
                              void* d_out, int out_size, void* d_ws, size_t ws_size,
                              hipStream_t stream) {
    const float* x = (const float*)d_in[0];   // [2,128,32,32]
    const float* W = (const float*)d_in[1];   // [16,16,16,3,3]
    float* out = (float*)d_out;               // [2,256,32,32]
    float* xT = (float*)d_ws;
    float* Wt = xT + XT_ELEMS;

    const size_t need = (size_t)(XT_ELEMS + WT_ELEMS) * sizeof(float);
    if (ws_size >= need) {
        prep_kernel<<<208, 256, 0, stream>>>(x, W, xT, Wt);
        capsule_v3<<<2048, 256, 0, stream>>>(xT, Wt, out);
    } else {
        capsule_fb<<<2048, 256, 0, stream>>>(x, W, out);
    }
}

// Round 7
// 97.185 us; speedup vs baseline: 1.3629x; 1.0465x over previous
//
#include <hip/hip_runtime.h>

// CapsuleConv2d fused, MI355X gfx950. ALL I/O FP32.
// B=2, C_in=128 (G=8 x M=16), 32x32, 3x3 pad 1, O=16, L=16 -> C_out=256.
// k-means (dot) routing 3 iters + squash.
//
// v4: 1 block/pixel. Phase 1 (thread=(o,l)): priors u[72] via SGPR patch
// (s_load from xT) x VGPR weights, v_pk_fma_f32 packed math. ONE LDS
// transpose (u invariant across iters). Phase 2 (thread=(o,nc)): thread owns
// 4-5 u-rows (all 16 l) in regs; routing register-local (15 exps/thread),
// v-updates via DPP 16-lane all-reduce.
// __launch_bounds__(256,1): full 512-reg unified budget -> NO scratch
// (R6 regression root cause: (256,3) capped budget at ~170 -> arrays spilled).

typedef float v2f __attribute__((ext_vector_type(2)));

#define NPRI 72
#define XT_ELEMS (2 * 32 * 32 * 128)   // 1 MB
#define WT_ELEMS (9 * 256 * 16)        // 576 KB
#define ROWSTR 264                     // LDS row stride (floats), 16B-aligned

#define DPP_ADD(a, ctrl)                                                     \
  a += __int_as_float(__builtin_amdgcn_update_dpp(                           \
          0, __float_as_int(a), ctrl, 0xF, 0xF, true))

__device__ __forceinline__ float dpp_add16(float x) {
    // sum across each aligned 16-lane group, broadcast to all 16 lanes.
    float s = x;
    DPP_ADD(s, 0x128); DPP_ADD(s, 0x124); DPP_ADD(s, 0x122); DPP_ADD(s, 0x121);
    return s;
}

__device__ __forceinline__ float frcp(float x) {
    return __builtin_amdgcn_rcpf(x);
}

__device__ __forceinline__ v2f pkfma(v2f a, v2f b, v2f c) {
    return __builtin_elementwise_fma(a, b, c);
}

// ---- prep: blocks [0,64) x-transpose, [64,208) weight transpose ----
// xT[b][h][w][c] = x[b][c][h][w];  Wt[(ij*256+t)*16+m] = W[(t*16+m)*9+ij]
__global__ __launch_bounds__(256)
void prep_kernel(const float* __restrict__ x, const float* __restrict__ W,
                 float* __restrict__ xT, float* __restrict__ Wt) {
    const int blk = blockIdx.x;
    const int tid = threadIdx.x;
    if (blk < 64) {
        __shared__ float xs[128 * 33];
        const int b = blk >> 5, h = blk & 31;
        const float* xb = x + b * (128 * 32 * 32) + h * 32;  // [c*1024 + w]
        #pragma unroll
        for (int k = 0; k < 16; ++k) {
            int idx = k * 256 + tid;
            int c = idx >> 5, w = idx & 31;
            xs[c * 33 + w] = xb[c * 1024 + w];   // coalesced read
        }
        __syncthreads();
        float* xo = xT + (b * 32 + h) * 32 * 128;
        #pragma unroll
        for (int k = 0; k < 16; ++k) {
            int idx = k * 256 + tid;
            int w = idx >> 7, c = idx & 127;
            xo[w * 128 + c] = xs[c * 33 + w];    // coalesced write, cf-free read
        }
    } else {
        int idx = (blk - 64) * 256 + tid;        // 0..36863
        int ij = idx >> 12;
        int r  = idx & 4095;
        int tt = r >> 4;
        int m  = r & 15;
        Wt[idx] = W[(tt * 16 + m) * 9 + ij];
    }
}

// ---- main kernel v4 ----
__global__ __launch_bounds__(256, 1)
void capsule_v4(const float* __restrict__ xT, const float* __restrict__ Wt,
                float* __restrict__ out) {
    __shared__ float uTs[36 * ROWSTR];       // 38.0 KB, two-chunk transpose
    const int pix = blockIdx.x;              // 2048
    const int b = pix >> 10, h = (pix >> 5) & 31, w = pix & 31;
    const int t = threadIdx.x;
    const int o = t >> 4, nc = t & 15;       // phase1: l == nc

    // ---- phase 1: priors u[n=g*9+ij], thread=(o,l), packed fp32 ----
    float u[NPRI];
    #pragma unroll
    for (int n = 0; n < NPRI; ++n) u[n] = 0.0f;

    #pragma unroll
    for (int ij = 0; ij < 9; ++ij) {
        const int di = ij / 3, dj = ij % 3;
        const int hh = h + di - 1, ww = w + dj - 1;
        if ((unsigned)hh < 32u && (unsigned)ww < 32u) {   // block-uniform
            const v2f* sp2 = (const v2f*)(xT + ((b * 32 + hh) * 32 + ww) * 128);
            const v2f* wp2 = (const v2f*)(Wt + (ij * 256 + t) * 16);
            v2f wr2[8];
            #pragma unroll
            for (int m = 0; m < 8; ++m) wr2[m] = wp2[m];
            #pragma unroll
            for (int g = 0; g < 8; ++g) {
                v2f acc = {0.0f, 0.0f};
                #pragma unroll
                for (int m = 0; m < 8; ++m)
                    acc = pkfma(sp2[g * 8 + m], wr2[m], acc);  // v_pk_fma_f32
                u[g * 9 + ij] = acc.x + acc.y;
            }
        }
    }

    // ---- transpose u via LDS (two 36-row chunks); thread owns n=nc+16k ----
    v2f ut2[5][8];
    #pragma unroll
    for (int j2 = 0; j2 < 8; ++j2) ut2[4][j2] = (v2f){0.0f, 0.0f};
    const bool has5 = (nc < 8);

    #pragma unroll
    for (int n = 0; n < 36; ++n) uTs[n * ROWSTR + t] = u[n];
    __syncthreads();
    {
        #pragma unroll
        for (int k = 0; k < 2; ++k) {        // n = nc, 16+nc (< 36 always)
            const v2f* r2 = (const v2f*)&uTs[(nc + 16 * k) * ROWSTR + o * 16];
            #pragma unroll
            for (int j2 = 0; j2 < 8; ++j2) ut2[k][j2] = r2[j2];
        }
        if (nc < 4) {                        // n = 32+nc in chunk 1
            const v2f* r2 = (const v2f*)&uTs[(32 + nc) * ROWSTR + o * 16];
            #pragma unroll
            for (int j2 = 0; j2 < 8; ++j2) ut2[2][j2] = r2[j2];
        }
    }
    __syncthreads();
    #pragma unroll
    for (int n = 36; n < NPRI; ++n) uTs[(n - 36) * ROWSTR + t] = u[n];
    __syncthreads();
    {
        if (nc >= 4) {                       // n = 32+nc -> chunk row nc-4
            const v2f* r2 = (const v2f*)&uTs[(nc - 4) * ROWSTR + o * 16];
            #pragma unroll
            for (int j2 = 0; j2 < 8; ++j2) ut2[2][j2] = r2[j2];
        }
        {                                    // n = 48+nc -> chunk row 12+nc
            const v2f* r2 = (const v2f*)&uTs[(12 + nc) * ROWSTR + o * 16];
            #pragma unroll
            for (int j2 = 0; j2 < 8; ++j2) ut2[3][j2] = r2[j2];
        }
        if (has5) {                          // n = 64+nc -> chunk row 28+nc
            const v2f* r2 = (const v2f*)&uTs[(28 + nc) * ROWSTR + o * 16];
            #pragma unroll
            for (int j2 = 0; j2 < 8; ++j2) ut2[4][j2] = r2[j2];
        }
    }

    // ---- init v = mean over n (ut2[4]=0 for !has5 lanes) ----
    v2f va2[8];
    #pragma unroll
    for (int j2 = 0; j2 < 8; ++j2) {
        v2f s = (ut2[0][j2] + ut2[1][j2]) + (ut2[2][j2] + ut2[3][j2]) + ut2[4][j2];
        va2[j2].x = dpp_add16(s.x) * (1.0f / NPRI);
        va2[j2].y = dpp_add16(s.y) * (1.0f / NPRI);
    }

    // ---- 3 routing iterations, registers only ----
    #pragma unroll 1
    for (int it = 0; it < 3; ++it) {
        v2f ssv = {0.0f, 0.0f};
        #pragma unroll
        for (int j2 = 0; j2 < 8; ++j2) ssv = pkfma(va2[j2], va2[j2], ssv);
        float ss = ssv.x + ssv.y;
        float inv = frcp(fmaxf(sqrtf(ss), 1e-12f));

        float e[5], ssum = 0.0f;
        #pragma unroll
        for (int k = 0; k < 5; ++k) {
            v2f d2 = {0.0f, 0.0f};
            #pragma unroll
            for (int j2 = 0; j2 < 8; ++j2) d2 = pkfma(ut2[k][j2], va2[j2], d2);
            float ek = __expf((d2.x + d2.y) * inv);
            if (k == 4) ek = has5 ? ek : 0.0f;
            e[k] = ek;
            ssum += ek;
        }
        ssum = dpp_add16(ssum);
        float rs = frcp(ssum);

        v2f e0 = {e[0], e[0]}, e1 = {e[1], e[1]}, e2v = {e[2], e[2]};
        v2f e3 = {e[3], e[3]}, e4 = {e[4], e[4]};
        #pragma unroll
        for (int j2 = 0; j2 < 8; ++j2) {
            v2f pv = e0 * ut2[0][j2];
            pv = pkfma(e1, ut2[1][j2], pv);
            pv = pkfma(e2v, ut2[2][j2], pv);
            pv = pkfma(e3, ut2[3][j2], pv);
            pv = pkfma(e4, ut2[4][j2], pv);
            va2[j2].x = dpp_add16(pv.x) * rs;
            va2[j2].y = dpp_add16(pv.y) * rs;
        }
    }

    // ---- squash ----
    v2f ssv = {0.0f, 0.0f};
    #pragma unroll
    for (int j2 = 0; j2 < 8; ++j2) ssv = pkfma(va2[j2], va2[j2], ssv);
    float ss = ssv.x + ssv.y;
    float scale = sqrtf(ss) * frcp(1.0f + ss);

    // select component l = nc: j2 = nc>>1, component = nc&1
    v2f c4[4], c2[2];
    #pragma unroll
    for (int j = 0; j < 4; ++j) c4[j] = (nc & 8) ? va2[j + 4] : va2[j];
    #pragma unroll
    for (int j = 0; j < 2; ++j) c2[j] = (nc & 4) ? c4[j + 2] : c4[j];
    v2f c1 = (nc & 2) ? c2[1] : c2[0];
    float res = ((nc & 1) ? c1.y : c1.x) * scale;

    out[((b * 256 + t) * 32 + h) * 32 + w] = res;
}

// ---- fallback (tiny ws): self-contained ----
__global__ __launch_bounds__(256, 1)
void capsule_fb(const float* __restrict__ x, const float* __restrict__ Wraw,
                float* __restrict__ out) {
    __shared__ float patch[9 * 128];
    const int blk = blockIdx.x;
    const int b = blk >> 10, h = (blk >> 5) & 31, w = blk & 31;
    const int t = threadIdx.x;

    const float* xb = x + b * (128 * 32 * 32);
    for (int idx = t; idx < 1152; idx += 256) {
        int c = idx / 9, ij = idx - c * 9;
        int di = ij / 3, dj = ij - di * 3;
        int hh = h + di - 1, ww = w + dj - 1;
        float v = 0.0f;
        if ((unsigned)hh < 32u && (unsigned)ww < 32u)
            v = xb[(c * 32 + hh) * 32 + ww];
        patch[ij * 128 + c] = v;
    }
    __syncthreads();

    float u[NPRI];
    #pragma unroll
    for (int ij = 0; ij < 9; ++ij) {
        float wr[16];
        #pragma unroll
        for (int m = 0; m < 16; ++m) wr[m] = Wraw[(t * 16 + m) * 9 + ij];
        #pragma unroll
        for (int g = 0; g < 8; ++g) {
            float acc = 0.0f;
            #pragma unroll
            for (int m = 0; m < 16; ++m)
                acc = fmaf(patch[ij * 128 + g * 16 + m], wr[m], acc);
            u[g * 9 + ij] = acc;
        }
    }

    float v = 0.0f;
    #pragma unroll
    for (int n = 0; n < NPRI; ++n) v += u[n];
    v *= (1.0f / NPRI);
    #pragma unroll 1
    for (int it = 0; it < 3; ++it) {
        float s = dpp_add16(v * v);
        float vn = v * frcp(fmaxf(sqrtf(s), 1e-12f));
        float ssum = 0.0f, vacc = 0.0f;
        #pragma unroll
        for (int n = 0; n < NPRI; ++n) {
            float p = dpp_add16(u[n] * vn);
            float e = __expf(p);
            ssum += e;
            vacc = fmaf(e, u[n], vacc);
        }
        v = vacc * frcp(ssum);
    }
    float s = dpp_add16(v * v);
    float res = v * sqrtf(s) * frcp(1.0f + s);
    out[((b * 256 + t) * 32 + h) * 32 + w] = res;
}

extern "C" void kernel_launch(void* const* d_in, const int* in_sizes, int n_in,
                              void* d_out, int out_size, void* d_ws, size_t ws_size,
                              hipStream_t stream) {
    const float* x = (const float*)d_in[0];   // [2,128,32,32]
    const float* W = (const float*)d_in[1];   // [16,16,16,3,3]
    float* out = (float*)d_out;               // [2,256,32,32]
    float* xT = (float*)d_ws;
    float* Wt = xT + XT_ELEMS;

    const size_t need = (size_t)(XT_ELEMS + WT_ELEMS) * sizeof(float);
    if (ws_size >= need) {
        prep_kernel<<<208, 256, 0, stream>>>(x, W, xT, Wt);
        capsule_v4<<<2048, 256, 0, stream>>>(xT, Wt, out);
    } else {
        capsule_fb<<<2048, 256, 0, stream>>>(x, W, out);
    }
}